// Round 1
// 231.524 us; speedup vs baseline: 1.0123x; 1.0123x over previous
//
#include <hip/hip_runtime.h>

// TV denoiser (Chambolle-Pock), 40 iterations = 5 launches x 8 fused steps.
// Temporal blocking: 64x64 staged region -> central 48x48 output (KF=8).
//
// Round-13: register diet -> 3 blocks/CU.
//   Theory: ~43 us/launch vs ~11-13 us VALU-issue floor at 16 waves/CU ->
//   latency/barrier-convoy bound at 50% occupancy. VGPR is the gate.
//   Diet: tm[8] -> 2 byte-packed VGPRs; ehf[8] -> single wave-uniform sigBot
//   (only (by==10, s==4, i==7) ever has ehf==0 on an ACTIVE cell; all other
//   ehf==0 rows are tm==0-frozen and v0 never escapes, all inputs finite so
//   fmaf(0,x,u)==u); ewf -> sewf=SIGMA*ewf folded into the fma; freeze via
//   r1/rh = act ? RHO/0.995 : 0 multipliers (1 cmp + 2 cndmask vs 3 cndmask,
//   and inner fmaf(v0,iv,-u0) absorbs the sub). Live state ~80 -> ~67.
//   __launch_bounds__(512,3): 2nd arg acts as blocks/CU (rounds 8/9) -> cap
//   ~85 VGPR, 24 waves/CU. Spill sentinel: WRITE_SIZE must stay 24.5 MB.
//
// Round-12 structure retained: wave = strip, cross-lane via __shfl (VERIFIED
// wave-wide on gfx950; DPP row-shifts mis-shift at 16-lane boundaries).
// 512 threads = 8 waves; wave s owns rows 8s..8s+7 of all 64 staged columns
// (thread = one column x 8 rows in REGISTERS). Vertical neighbors: registers.
// Horizontal: __shfl_up(u1,1) [phase 1] / __shfl_down(w,1) [phase 2].
// Lane-edge clamp garbage is harmless: columns lc=0/63 have tm=0 and their w
// feeds only inactive cells (cone argument, rounds 8-10). Strip boundaries
// cross waves via stride-1 LDS u0B/wTop (4.6 KB, conflict-free).
// first=1: u==0, x2==y (no memset). last=1: skip u stores.

#define Hh 512
#define Ww 512
#define Bb 8
#define TS 48
#define KF 8
#define S  64
#define NT 512
#define RS 8           // rows per strip = rows per thread

__global__ __launch_bounds__(NT, 3)
void tv_fused(const float*  __restrict__ x2_in,
              const float2* __restrict__ u_in,
              const float*  __restrict__ y_in,
              float*  __restrict__ x2_out,
              float2* __restrict__ u_out,
              int first, int last)
{
    constexpr float TAU = 0.01f;
    constexpr float RHO = 1.99f;
    constexpr float HRHO = 0.995f;       // 0.5*RHO
    constexpr float SIGMA = 12.5f;       // 1/TAU/8
    constexpr float THS = 0.1f;
    constexpr float INV_1PT = 1.0f / 1.01f;

    __shared__ float u0B [9 * S];   // u0B[s][lc] = u0 of row 8s-1 (strip s-1 bottom); s=0 zeros
    __shared__ float wTop[9 * S];   // wTop[s][lc] = w of row 8s (strip s top); s=8 zeros

    const int b   = blockIdx.z;
    const int r0  = blockIdx.y * TS;
    const int c0  = blockIdx.x * TS;
    const int tid = threadIdx.x;
    const size_t plane = (size_t)b * (Hh * Ww);

    const int s   = tid >> 6;            // 0..7 == wave id
    const int lc  = tid & 63;            // 0..63 == lane id
    const int gc  = c0 - KF + lc;
    const bool colin = (gc >= 0) & (gc < Ww);
    const float sewf = (gc < Ww - 1) ? SIGMA : 0.f;   // folded SIGMA*ewf
    const int lr0 = RS * s;
    const int gr0 = r0 - KF + lr0;
    // ehf==0 on an ACTIVE cell happens only at gr==Hh-1, i.e. gr0+RS-1==Hh-1
    // (unique: by==10, s==4, i==7). All other ehf==0 rows are frozen (tm==0).
    const float sigBot = (gr0 + RS - 1 == Hh - 1) ? 0.f : SIGMA;

    if (tid < S) { u0B[tid] = 0.f; wTop[8 * S + tid] = 0.f; }

    float u0[RS], u1[RS], x2[RS], yv[RS], w[RS];
    unsigned tmp0 = 0u, tmp1 = 0u;       // tm[0..3], tm[4..7] byte-packed (tm <= 31)

    // ---- stage: global -> registers
    #pragma unroll
    for (int i = 0; i < RS; ++i) {
        const int gr = gr0 + i;
        const int lr = lr0 + i;
        const bool img = colin & (gr >= 0) & (gr < Hh);
        float a = 0.f, c = 0.f, z0 = 0.f, z1 = 0.f;
        if (img) {
            size_t gi = plane + (size_t)gr * Ww + gc;
            c = y_in[gi];
            if (first) a = c;
            else {
                a = x2_in[gi];
                float2 uu = u_in[gi];
                z0 = uu.x; z1 = uu.y;
            }
        }
        u0[i] = z0; u1[i] = z1; x2[i] = a; yv[i] = c;
        unsigned tm = img ? (unsigned)min(min(lr, S - 1 - lr), min(lc, S - 1 - lc)) : 0u;
        if (i < 4) tmp0 |= tm << (8 * i);
        else       tmp1 |= tm << (8 * (i - 4));
    }
    u0B[(s + 1) * S + lc] = u0[RS - 1];
    __syncthreads();

    for (int t = 0; t < KF; ++t) {
        // ---- phase 1: w = 2x - x2 (unconditional; garbage never escapes cone)
        {
            float u0a = u0B[s * S + lc];
            #pragma unroll
            for (int i = 0; i < RS; ++i) {
                float ul = __shfl_up(u1[i], 1, 64);      // u1 of col lc-1 (lane 0: own value; col 0 w feeds only inactive cells)
                float ua = (i == 0) ? u0a : u0[i - 1];
                float adj = ua - u0[i] + ul - u1[i];
                float xv = fmaf(TAU, yv[i] - adj, x2[i]);    // x*(1+TAU)
                w[i] = fmaf(2.0f * INV_1PT, xv, -x2[i]);     // 2x - x2
            }
            wTop[s * S + lc] = w[0];
        }
        __syncthreads();
        // ---- phase 2: u, x2 update (freeze inactive/OOB cells via r1/rh=0)
        {
            float wbot = wTop[(s + 1) * S + lc];
            #pragma unroll
            for (int i = 0; i < RS; ++i) {
                float wr = __shfl_down(w[i], 1, 64);     // w of col lc+1 (lane 63: own value; cell 63 inactive)
                float wb = (i == RS - 1) ? wbot : w[i + 1];
                const float sig_h = (i == RS - 1) ? sigBot : SIGMA;
                float v0 = fmaf(sig_h, wb - w[i], u0[i]);
                float v1 = fmaf(sewf,  wr - w[i], u1[i]);
                float iv = fminf(THS * __builtin_amdgcn_rsqf(fmaf(v0, v0, v1 * v1)), 1.f);
                unsigned tmb = ((i < 4 ? tmp0 : tmp1) >> (8 * (i & 3))) & 255u;
                bool act = (unsigned)t < tmb;
                float r1 = act ? RHO  : 0.f;
                float rh = act ? HRHO : 0.f;
                // all operands finite even when frozen (staged OOB = 0, shfl
                // clamp returns own value, rsq(0)->inf dies in fmin) so the
                // +0*expr freeze is NaN-safe.
                u0[i] = fmaf(r1, fmaf(v0, iv, -u0[i]), u0[i]);
                u1[i] = fmaf(r1, fmaf(v1, iv, -u1[i]), u1[i]);
                x2[i] = fmaf(rh, w[i] - x2[i], x2[i]);
            }
            u0B[(s + 1) * S + lc] = u0[RS - 1];
        }
        __syncthreads();
    }

    // ---- store central 48x48 straight from registers
    if (s >= 1 && s <= 6 && lc >= KF && lc < KF + TS && gc < Ww) {
        #pragma unroll
        for (int i = 0; i < RS; ++i) {
            const int gr = gr0 + i;
            if (gr < Hh) {
                size_t gi = plane + (size_t)gr * Ww + gc;
                x2_out[gi] = x2[i];
                if (!last) u_out[gi] = make_float2(u0[i], u1[i]);
            }
        }
    }
}

extern "C" void kernel_launch(void* const* d_in, const int* in_sizes, int n_in,
                              void* d_out, int out_size, void* d_ws, size_t ws_size,
                              hipStream_t stream)
{
    const float* y = (const float*)d_in[0];
    float* out = (float*)d_out;
    const size_t NP = (size_t)Bb * Hh * Ww;   // 2M cells

    float*  ws  = (float*)d_ws;
    float*  x2A = ws;                          // 8 MB
    float*  x2B = ws + NP;                     // 8 MB
    float2* uA  = (float2*)(ws + 2 * NP);      // 16 MB
    float2* uB  = (float2*)(ws + 4 * NP);      // 16 MB
    // total ws use: 48 MB; no memset (first=1 treats u as 0, x2 as y)

    dim3 grid((Ww + TS - 1) / TS, (Hh + TS - 1) / TS, Bb);   // 11 x 11 x 8 = 968 blocks

    tv_fused<<<grid, NT, 0, stream>>>(y,   uB, y, x2A, uA, 1, 0);
    tv_fused<<<grid, NT, 0, stream>>>(x2A, uA, y, x2B, uB, 0, 0);
    tv_fused<<<grid, NT, 0, stream>>>(x2B, uB, y, x2A, uA, 0, 0);
    tv_fused<<<grid, NT, 0, stream>>>(x2A, uA, y, x2B, uB, 0, 0);
    tv_fused<<<grid, NT, 0, stream>>>(x2B, uB, y, out, uA, 0, 1);
}